// Round 6
// baseline (277.700 us; speedup 1.0000x reference)
//
#include <hip/hip_runtime.h>
#include <hip/hip_bf16.h>
#include <math.h>

#define M_ROWS 16384
#define DIM 1024

typedef __attribute__((ext_vector_type(8))) short short8;
typedef __attribute__((ext_vector_type(4))) float f32x4;

#define MFMA_BF16(a, b, c) __builtin_amdgcn_mfma_f32_16x16x32_bf16(a, b, c, 0, 0, 0)

#define GLOAD16(gp, lp) __builtin_amdgcn_global_load_lds( \
    (const __attribute__((address_space(1))) unsigned int*)(gp), \
    (__attribute__((address_space(3))) unsigned int*)(lp), 16, 0, 0)

__device__ __forceinline__ short bf16_hi(float x) {
    return (short)__bfloat16_as_ushort(__float2bfloat16(x));
}
__device__ __forceinline__ float bf16_f(short s) {
    return __bfloat162float(__ushort_as_bfloat16((unsigned short)s));
}

__device__ __forceinline__ float fast_asinh(float x) {
    float ax = fabsf(x);
    float r = __logf(ax + sqrtf(fmaf(ax, ax, 1.0f)));
    return copysignf(r, x);
}
__device__ __forceinline__ float fast_sinh(float x) {
    float e = __expf(x), em = __expf(-x);
    return 0.5f * (e - em);
}

__device__ __forceinline__ float waveReduceSum(float v) {
#pragma unroll
    for (int off = 32; off > 0; off >>= 1) v += __shfl_down(v, off, 64);
    return v;
}

// ---- column norms of weigh_v (axis=0) ----
__global__ void colnorm_partial(const float* __restrict__ W, float* __restrict__ part) {
    int col = (blockIdx.x & 3) * 256 + threadIdx.x;
    int r0 = (blockIdx.x >> 2) * 128;
    float s = 0.f;
#pragma unroll 8
    for (int i = 0; i < 128; ++i) {
        float t = W[(size_t)(r0 + i) * DIM + col];
        s += t * t;
    }
    part[(size_t)(blockIdx.x >> 2) * DIM + col] = s;
}

__global__ void colnorm_final(const float* __restrict__ part, float* __restrict__ invn) {
    int col = blockIdx.x * 256 + threadIdx.x;
    float s = 0.f;
#pragma unroll
    for (int p = 0; p < 8; ++p) s += part[(size_t)p * DIM + col];
    float n = fminf(fmaxf(sqrtf(s), 1e-6f), 1e6f);
    invn[col] = 1.0f / n;
}

// ---- transpose + bf16 hi/lo split of weigh_v into interleaved layout ----
// Bws[n][kb][0..31]=hi shorts, [32..63]=lo shorts  (row stride 2048 shorts)
__global__ __launch_bounds__(256) void wsplit(const float* __restrict__ W,
                                              short* __restrict__ Bws) {
    __shared__ float tile[64][65];
    const int t = threadIdx.x;
    const int k0 = (blockIdx.x >> 4) * 64, n0 = (blockIdx.x & 15) * 64;
    const int rk = t >> 4;          // 0..15
    const int cn = (t & 15) * 4;    // 0..60
#pragma unroll
    for (int p = 0; p < 4; ++p) {
        float4 v = *(const float4*)&W[(size_t)(k0 + rk + p * 16) * DIM + n0 + cn];
        tile[rk + p * 16][cn + 0] = v.x;
        tile[rk + p * 16][cn + 1] = v.y;
        tile[rk + p * 16][cn + 2] = v.z;
        tile[rk + p * 16][cn + 3] = v.w;
    }
    __syncthreads();
    const int rn = t >> 4;
    const int ck = (t & 15) * 4;          // 0..60, 4 k within one 32-chunk
    const int kbl = (t & 15) >> 3;        // 0 or 1
    const int ko = (t & 7) * 4;           // ck & 31
#pragma unroll
    for (int p = 0; p < 4; ++p) {
        int n = rn + p * 16;
        union { short s[4]; uint2 u; } ph, pl;
#pragma unroll
        for (int e = 0; e < 4; ++e) {
            float a = tile[ck + e][n];
            short h = bf16_hi(a);
            ph.s[e] = h;
            pl.s[e] = bf16_hi(a - bf16_f(h));
        }
        size_t base = (size_t)(n0 + n) * 2048 + (size_t)(k0 >> 5) * 64 + kbl * 64;
        *(uint2*)&Bws[base + ko]      = ph.u;
        *(uint2*)&Bws[base + 32 + ko] = pl.u;
    }
}

// ---- per-row prep into interleaved layout: Aws[row][kb][hi32|lo32] ----
__global__ __launch_bounds__(256) void rowprep_split(
    const float* __restrict__ in, const float* __restrict__ cptr,
    short* __restrict__ Aws, float* __restrict__ cx2) {
    const int row = blockIdx.x, t = threadIdx.x;
    float4 v = ((const float4*)(in + (size_t)row * DIM))[t];
    float s = v.x * v.x + v.y * v.y + v.z * v.z + v.w * v.w;
    s = waveReduceSum(s);
    __shared__ float red[4];
    __shared__ float rsv_sh;
    int wid = t >> 6, lane = t & 63;
    if (lane == 0) red[wid] = s;
    __syncthreads();
    if (t == 0) {
        float stot = red[0] + red[1] + red[2] + red[3];
        float cc = cptr[0], rc = sqrtf(cc);
        float un = sqrtf(fmaxf(stot, 1e-15f));          // _safe_norm(u)
        float xs = tanhf(rc * un) / (rc * un);          // x = xs*u
        float xn = sqrtf(fmaxf(xs * xs * stot, 1e-15f));
        float mn = (1.0f - 1e-5f) / rc;
        float pf = (xn > mn) ? (mn / xn) : 1.0f;        // proj
        float rsv = rc * xs * pf;                       // rcx = rsv*u
        rsv_sh = rsv;
        cx2[row] = rsv * rsv * stot;
    }
    __syncthreads();
    float rsv = rsv_sh;
    float a[4] = {v.x * rsv, v.y * rsv, v.z * rsv, v.w * rsv};
    union { short s[4]; uint2 u; } ph, pl;
#pragma unroll
    for (int e = 0; e < 4; ++e) {
        short h = bf16_hi(a[e]);
        ph.s[e] = h;
        pl.s[e] = bf16_hi(a[e] - bf16_f(h));
    }
    const int kb = t >> 3;          // (t*4)>>5
    const int ko = (t & 7) * 4;
    size_t base = (size_t)row * 2048 + kb * 64;
    *(uint2*)&Aws[base + ko]      = ph.u;
    *(uint2*)&Aws[base + 32 + ko] = pl.u;
}

// ---- MFMA GEMM (bf16x3), 256x256 tile, 8 waves (2x4, 128x64 each), BK=32 ----
// Double-buffered LDS, single __syncthreads per K-step (2-phase pipeline).
// LDS rows: [256 rows][8 slots of 16B] (slots 0-3 hi, 4-7 lo), slot ^= row&7.
__global__ __launch_bounds__(512) void gemm_mfma(
    const short* __restrict__ Aws, const short* __restrict__ Bws,
    const float* __restrict__ cx2, const float* __restrict__ invn,
    const float* __restrict__ wg, const float* __restrict__ bias,
    const float* __restrict__ cptr, float* __restrict__ Y) {
    __shared__ char smem[128 * 1024];
    short* sAB[4];
    sAB[0] = (short*)smem;                  // A buf0: 32 KB (256 x 64 shorts)
    sAB[1] = (short*)(smem + 32768);        // B buf0
    sAB[2] = (short*)(smem + 65536);        // A buf1
    sAB[3] = (short*)(smem + 98304);        // B buf1

    // 256 blocks (64 row-blocks x 4 col-blocks); XCD-chunked swizzle
    const int j = blockIdx.x;
    const int by = (j & 7) * 8 + ((j >> 3) >> 2);
    const int bx = (j >> 3) & 3;
    const int row0 = by * 256, col0 = bx * 256;

    const int t = threadIdx.x;              // 0..511
    const int l = t & 63, w = t >> 6;       // 8 waves
    const int wr = (w >> 2) * 128, wc = (w & 3) * 64;
    const int fr = l & 15, fk3 = l >> 4;

    // staging: thread t -> row row_t (0..63) of each 64-row chunk, slot t&7
    const int row_t = t >> 3;
    const int slotA = ((t & 7) ^ (row_t & 7)) * 8;      // pre-swizzled source slot
    const size_t gA0 = (size_t)(row0 + row_t) * 2048 + slotA;
    const size_t gB0 = (size_t)(col0 + row_t) * 2048 + slotA;

    f32x4 acc[8][4] = {};

    // prologue: stage tile 0 into buf0
#pragma unroll
    for (int p = 0; p < 4; ++p) {
        GLOAD16(Aws + gA0 + (size_t)p * 131072, sAB[0] + p * 4096 + t * 8);
        GLOAD16(Bws + gB0 + (size_t)p * 131072, sAB[1] + p * 4096 + t * 8);
    }
    __syncthreads();

    for (int tt = 0; tt < 32; ++tt) {
        const short* sAc = sAB[(tt & 1) * 2];
        const short* sBc = sAB[(tt & 1) * 2 + 1];
        if (tt < 31) {
            short* sAn = sAB[((tt + 1) & 1) * 2];
            short* sBn = sAB[((tt + 1) & 1) * 2 + 1];
            const int kbo = (tt + 1) * 64;
#pragma unroll
            for (int p = 0; p < 4; ++p) {
                GLOAD16(Aws + gA0 + (size_t)p * 131072 + kbo, sAn + p * 4096 + t * 8);
                GLOAD16(Bws + gB0 + (size_t)p * 131072 + kbo, sBn + p * 4096 + t * 8);
            }
        }
        short8 ah[8], al[8], bh[4], bl[4];
#pragma unroll
        for (int i = 0; i < 8; ++i) {
            int r = wr + i * 16 + fr;
            int rb = r * 64, rx = r & 7;
            ah[i] = *(const short8*)&sAc[rb + ((fk3 ^ rx) << 3)];
            al[i] = *(const short8*)&sAc[rb + (((4 | fk3) ^ rx) << 3)];
        }
#pragma unroll
        for (int n = 0; n < 4; ++n) {
            int r = wc + n * 16 + fr;
            int rb = r * 64, rx = r & 7;
            bh[n] = *(const short8*)&sBc[rb + ((fk3 ^ rx) << 3)];
            bl[n] = *(const short8*)&sBc[rb + (((4 | fk3) ^ rx) << 3)];
        }
        __builtin_amdgcn_s_setprio(1);
#pragma unroll
        for (int i = 0; i < 8; ++i)
#pragma unroll
            for (int n = 0; n < 4; ++n) {
                acc[i][n] = MFMA_BF16(ah[i], bh[n], acc[i][n]);
                acc[i][n] = MFMA_BF16(ah[i], bl[n], acc[i][n]);
                acc[i][n] = MFMA_BF16(al[i], bh[n], acc[i][n]);
            }
        __builtin_amdgcn_s_setprio(0);
        __syncthreads();   // drains prefetch vmcnt + guards both LDS hazards
    }

    // ---- epilogue: math in fragment layout, per-wave LDS slab -> coalesced ----
    const float cv = cptr[0];
    const float rcv = sqrtf(cv);
    const float inv_rc = 1.0f / rcv;
    const int fc = l & 15, fq = (l >> 4) * 4;

    float cxr[32];
#pragma unroll
    for (int i = 0; i < 8; ++i)
#pragma unroll
        for (int q = 0; q < 4; ++q)
            cxr[i * 4 + q] = cx2[row0 + wr + i * 16 + fq + q];

    float chf[4], shf[4], wff[4];
#pragma unroll
    for (int n = 0; n < 4; ++n) {
        const int col = col0 + wc + n * 16 + fc;
        float dr = 2.0f * rcv * bias[col];
        chf[n] = coshf(dr) * 2.0f * invn[col];   // folds 2*invn
        shf[n] = sinhf(dr);
        wff[n] = 2.0f * wg[col] * inv_rc;
    }

    // per-wave slab: 16 rows x 64 cols, stride 68 floats, 4.25 KB of 8 KB space
    float* slab = (float*)(smem + w * 8192);
    const int rr = l >> 4;          // 0..3 (read-phase row group)
    const int rc16 = l & 15;        // 0..15 (read-phase col group)

#pragma unroll
    for (int i = 0; i < 8; ++i) {
#pragma unroll
        for (int n = 0; n < 4; ++n)
#pragma unroll
            for (int q = 0; q < 4; ++q) {
                float a = acc[i][n][q];
                float mlr = fmaf(a, chf[n], -(1.0f + cxr[i * 4 + q]) * shf[n]);
                float wv = wff[n] * fast_asinh(mlr);
                slab[(fq + q) * 68 + n * 16 + fc] = fast_sinh(rcv * wv) * inv_rc;
            }
        __syncthreads();
#pragma unroll
        for (int p = 0; p < 4; ++p) {
            float4 v4 = *(const float4*)&slab[(p * 4 + rr) * 68 + rc16 * 4];
            *(float4*)&Y[(size_t)(row0 + wr + i * 16 + p * 4 + rr) * DIM +
                         col0 + wc + rc16 * 4] = v4;
        }
        __syncthreads();
    }
}

// ---- per-row finalize: denom + relu-in-tangent + logmap0 ----
__global__ void finalize(float* __restrict__ Y, const float* __restrict__ cptr) {
    int row = blockIdx.x;
    float4* rp = (float4*)(Y + (size_t)row * DIM);
    float4 v = rp[threadIdx.x];
    float s1 = v.x * v.x + v.y * v.y + v.z * v.z + v.w * v.w;
    float rx = fmaxf(v.x, 0.f), ryy = fmaxf(v.y, 0.f);
    float rz = fmaxf(v.z, 0.f), rw = fmaxf(v.w, 0.f);
    float s2 = rx * rx + ryy * ryy + rz * rz + rw * rw;
    s1 = waveReduceSum(s1);
    s2 = waveReduceSum(s2);
    __shared__ float red1[4], red2[4];
    int wid = threadIdx.x >> 6, lane = threadIdx.x & 63;
    if (lane == 0) { red1[wid] = s1; red2[wid] = s2; }
    __syncthreads();
    s1 = red1[0] + red1[1] + red1[2] + red1[3];
    s2 = red2[0] + red2[1] + red2[2] + red2[3];

    const float c = cptr[0];
    const float rc = sqrtf(c);
    float g = 1.0f / (1.0f + sqrtf(1.0f + c * s1));     // x = g*y
    float xn = sqrtf(fmaxf(g * g * s1, 1e-15f));
    float arg = fminf(rc * xn, 1.0f - 1e-7f);
    float f1 = atanhf(arg) / (rc * xn);                  // u = f1*x
    float fv = f1 * g;                                   // v = fv*relu(y)
    float vn = sqrtf(fmaxf(fv * fv * s2, 1e-15f));
    float f2 = tanhf(rc * vn) / (rc * vn);               // e = f2*v
    float en = sqrtf(fmaxf(f2 * f2 * fv * fv * s2, 1e-15f));
    float maxnorm = (1.0f - 1e-5f) / rc;
    float pf = (en > maxnorm) ? (maxnorm / en) : 1.0f;   // z = pf*e
    float zn = sqrtf(fmaxf(pf * pf * f2 * f2 * fv * fv * s2, 1e-15f));
    float arg2 = fminf(rc * zn, 1.0f - 1e-7f);
    float f3 = atanhf(arg2) / (rc * zn);                 // out = f3*z
    float F = f3 * pf * f2 * fv;

    rp[threadIdx.x] = make_float4(F * rx, F * ryy, F * rz, F * rw);
}

extern "C" void kernel_launch(void* const* d_in, const int* in_sizes, int n_in,
                              void* d_out, int out_size, void* d_ws, size_t ws_size,
                              hipStream_t stream) {
    const float* inputs   = (const float*)d_in[0];
    const float* weigh_v  = (const float*)d_in[1];
    const float* weight_g = (const float*)d_in[2];
    const float* bias     = (const float*)d_in[3];
    const float* cptr     = (const float*)d_in[4];
    float* Y = (float*)d_out;

    // workspace layout (assumes ws_size >= ~69 MB)
    char* ws = (char*)d_ws;
    short* Aws = (short*)ws;                                      // 64 MB
    short* Bws = (short*)(ws + (size_t)64 * 1024 * 1024);         // 4 MB
    float* invn    = (float*)(ws + (size_t)68 * 1024 * 1024);     // 4 KB
    float* cx2     = (float*)(ws + (size_t)68 * 1024 * 1024 + 65536);   // 64 KB
    float* colpart = (float*)(ws + (size_t)68 * 1024 * 1024 + 131072);  // 32 KB

    colnorm_partial<<<32, 256, 0, stream>>>(weigh_v, colpart);
    colnorm_final<<<4, 256, 0, stream>>>(colpart, invn);
    wsplit<<<256, 256, 0, stream>>>(weigh_v, Bws);
    rowprep_split<<<M_ROWS, 256, 0, stream>>>(inputs, cptr, Aws, cx2);

    gemm_mfma<<<256, 512, 0, stream>>>(Aws, Bws, cx2, invn,
                                       weight_g, bias, cptr, Y);

    finalize<<<M_ROWS, 256, 0, stream>>>(Y, cptr);
}

// Round 7
// 183.460 us; speedup vs baseline: 1.5137x; 1.5137x over previous
//
#include <hip/hip_runtime.h>
#include <hip/hip_bf16.h>
#include <math.h>

#define M_ROWS 16384
#define DIM 1024

typedef __attribute__((ext_vector_type(8))) short short8;
typedef __attribute__((ext_vector_type(4))) float f32x4;

#define MFMA_BF16(a, b, c) __builtin_amdgcn_mfma_f32_16x16x32_bf16(a, b, c, 0, 0, 0)

#define GLOAD16(gp, lp) __builtin_amdgcn_global_load_lds( \
    (const __attribute__((address_space(1))) unsigned int*)(gp), \
    (__attribute__((address_space(3))) unsigned int*)(lp), 16, 0, 0)

__device__ __forceinline__ short bf16_hi(float x) {
    return (short)__bfloat16_as_ushort(__float2bfloat16(x));
}
__device__ __forceinline__ float bf16_f(short s) {
    return __bfloat162float(__ushort_as_bfloat16((unsigned short)s));
}

__device__ __forceinline__ float fast_asinh(float x) {
    float ax = fabsf(x);
    float r = __logf(ax + sqrtf(fmaf(ax, ax, 1.0f)));
    return copysignf(r, x);
}
__device__ __forceinline__ float fast_sinh(float x) {
    float e = __expf(x), em = __expf(-x);
    return 0.5f * (e - em);
}

__device__ __forceinline__ float waveReduceSum(float v) {
#pragma unroll
    for (int off = 32; off > 0; off >>= 1) v += __shfl_down(v, off, 64);
    return v;
}

// ---- column norms of weigh_v (axis=0) ----
__global__ void colnorm_partial(const float* __restrict__ W, float* __restrict__ part) {
    int col = (blockIdx.x & 3) * 256 + threadIdx.x;
    int r0 = (blockIdx.x >> 2) * 128;
    float s = 0.f;
#pragma unroll 8
    for (int i = 0; i < 128; ++i) {
        float t = W[(size_t)(r0 + i) * DIM + col];
        s += t * t;
    }
    part[(size_t)(blockIdx.x >> 2) * DIM + col] = s;
}

__global__ void colnorm_final(const float* __restrict__ part, float* __restrict__ invn) {
    int col = blockIdx.x * 256 + threadIdx.x;
    float s = 0.f;
#pragma unroll
    for (int p = 0; p < 8; ++p) s += part[(size_t)p * DIM + col];
    float n = fminf(fmaxf(sqrtf(s), 1e-6f), 1e6f);
    invn[col] = 1.0f / n;
}

// ---- transpose + bf16 hi/lo split of weigh_v into interleaved layout ----
// Bws[n][kb][0..31]=hi shorts, [32..63]=lo shorts  (row stride 2048 shorts)
__global__ __launch_bounds__(256) void wsplit(const float* __restrict__ W,
                                              short* __restrict__ Bws) {
    __shared__ float tile[64][65];
    const int t = threadIdx.x;
    const int k0 = (blockIdx.x >> 4) * 64, n0 = (blockIdx.x & 15) * 64;
    const int rk = t >> 4;          // 0..15
    const int cn = (t & 15) * 4;    // 0..60
#pragma unroll
    for (int p = 0; p < 4; ++p) {
        float4 v = *(const float4*)&W[(size_t)(k0 + rk + p * 16) * DIM + n0 + cn];
        tile[rk + p * 16][cn + 0] = v.x;
        tile[rk + p * 16][cn + 1] = v.y;
        tile[rk + p * 16][cn + 2] = v.z;
        tile[rk + p * 16][cn + 3] = v.w;
    }
    __syncthreads();
    const int rn = t >> 4;
    const int ck = (t & 15) * 4;          // 0..60, 4 k within one 32-chunk
    const int kbl = (t & 15) >> 3;        // 0 or 1
    const int ko = (t & 7) * 4;           // ck & 31
#pragma unroll
    for (int p = 0; p < 4; ++p) {
        int n = rn + p * 16;
        union { short s[4]; uint2 u; } ph, pl;
#pragma unroll
        for (int e = 0; e < 4; ++e) {
            float a = tile[ck + e][n];
            short h = bf16_hi(a);
            ph.s[e] = h;
            pl.s[e] = bf16_hi(a - bf16_f(h));
        }
        size_t base = (size_t)(n0 + n) * 2048 + (size_t)(k0 >> 5) * 64 + kbl * 64;
        *(uint2*)&Bws[base + ko]      = ph.u;
        *(uint2*)&Bws[base + 32 + ko] = pl.u;
    }
}

// ---- per-row prep into interleaved layout: Aws[row][kb][hi32|lo32] ----
__global__ __launch_bounds__(256) void rowprep_split(
    const float* __restrict__ in, const float* __restrict__ cptr,
    short* __restrict__ Aws, float* __restrict__ cx2) {
    const int row = blockIdx.x, t = threadIdx.x;
    float4 v = ((const float4*)(in + (size_t)row * DIM))[t];
    float s = v.x * v.x + v.y * v.y + v.z * v.z + v.w * v.w;
    s = waveReduceSum(s);
    __shared__ float red[4];
    __shared__ float rsv_sh;
    int wid = t >> 6, lane = t & 63;
    if (lane == 0) red[wid] = s;
    __syncthreads();
    if (t == 0) {
        float stot = red[0] + red[1] + red[2] + red[3];
        float cc = cptr[0], rc = sqrtf(cc);
        float un = sqrtf(fmaxf(stot, 1e-15f));          // _safe_norm(u)
        float xs = tanhf(rc * un) / (rc * un);          // x = xs*u
        float xn = sqrtf(fmaxf(xs * xs * stot, 1e-15f));
        float mn = (1.0f - 1e-5f) / rc;
        float pf = (xn > mn) ? (mn / xn) : 1.0f;        // proj
        float rsv = rc * xs * pf;                       // rcx = rsv*u
        rsv_sh = rsv;
        cx2[row] = rsv * rsv * stot;
    }
    __syncthreads();
    float rsv = rsv_sh;
    float a[4] = {v.x * rsv, v.y * rsv, v.z * rsv, v.w * rsv};
    union { short s[4]; uint2 u; } ph, pl;
#pragma unroll
    for (int e = 0; e < 4; ++e) {
        short h = bf16_hi(a[e]);
        ph.s[e] = h;
        pl.s[e] = bf16_hi(a[e] - bf16_f(h));
    }
    const int kb = t >> 3;          // (t*4)>>5
    const int ko = (t & 7) * 4;
    size_t base = (size_t)row * 2048 + kb * 64;
    *(uint2*)&Aws[base + ko]      = ph.u;
    *(uint2*)&Aws[base + 32 + ko] = pl.u;
}

// ---- MFMA GEMM (bf16x3), 256x128 tile, 8 waves (4x2 of 64x64), BK=32 ----
// 3-buffer LDS ring, counted vmcnt(6) (T3+T4): loads stay in flight across
// the single raw s_barrier per K-step; prefetch depth 2 K-steps.
// LDS rows: [rows][8 slots of 16B] (slots 0-3 hi, 4-7 lo), slot ^= row&7.
__global__ __launch_bounds__(512, 2) void gemm_mfma(
    const short* __restrict__ Aws, const short* __restrict__ Bws,
    const float* __restrict__ cx2, const float* __restrict__ invn,
    const float* __restrict__ wg, const float* __restrict__ bias,
    const float* __restrict__ cptr, float* __restrict__ Y) {
    __shared__ char smem[147456];   // 3 units x (A 32 KB + B 16 KB)

    // 512 wgs = 64 by x 8 bx; XCD-chunked swizzle (512 % 8 == 0, bijective)
    const int j = blockIdx.x;
    const int wgid = (j & 7) * 64 + (j >> 3);
    const int by = wgid >> 3, bx = wgid & 7;
    const int row0 = by * 256, col0 = bx * 128;

    const int t = threadIdx.x;              // 0..511
    const int l = t & 63, w = t >> 6;       // 8 waves
    const int wr = (w >> 1) * 64, wc = (w & 1) * 64;
    const int fr = l & 15, fk3 = l >> 4;

    // staging: thread t -> row t>>3 of each 64-row chunk, lds slot t&7
    const int row_t = t >> 3;
    const int slotA = ((t & 7) ^ (row_t & 7)) * 8;      // pre-swizzled source slot
    const size_t gA0 = (size_t)(row0 + row_t) * 2048 + slotA;
    const size_t gB0 = (size_t)(col0 + row_t) * 2048 + slotA;

    // 6 loads per K-step: A = 4x64 rows, B = 2x64 rows
#define STAGE(u, s) do { \
        short* dA = (short*)(smem + (u) * 49152); \
        short* dB = (short*)(smem + (u) * 49152 + 32768); \
        const int kbo = (s) * 64; \
        GLOAD16(Aws + gA0 + kbo,          dA + t * 8); \
        GLOAD16(Aws + gA0 + 131072 + kbo, dA + 4096 + t * 8); \
        GLOAD16(Aws + gA0 + 262144 + kbo, dA + 8192 + t * 8); \
        GLOAD16(Aws + gA0 + 393216 + kbo, dA + 12288 + t * 8); \
        GLOAD16(Bws + gB0 + kbo,          dB + t * 8); \
        GLOAD16(Bws + gB0 + 131072 + kbo, dB + 4096 + t * 8); \
    } while (0)

    f32x4 acc[4][4] = {};

    // prologue: stage steps 0,1; wait step 0 (oldest 6), keep 6 in flight
    STAGE(0, 0);
    STAGE(1, 1);
    asm volatile("s_waitcnt vmcnt(6)" ::: "memory");
    __builtin_amdgcn_s_barrier();

    for (int s = 0; s < 32; ++s) {
        if (s < 30) STAGE((s + 2) % 3, s + 2);   // buf (s+2)%3 freed by end-of-(s-1) barrier

        const short* sA = (const short*)(smem + (s % 3) * 49152);
        const short* sB = (const short*)(smem + (s % 3) * 49152 + 32768);

        short8 ah[4], al[4], bh[4], bl[4];
#pragma unroll
        for (int i = 0; i < 4; ++i) {
            int r = wr + i * 16 + fr;
            int rb = r * 64, rx = r & 7;
            ah[i] = *(const short8*)&sA[rb + ((fk3 ^ rx) << 3)];
            al[i] = *(const short8*)&sA[rb + (((4 | fk3) ^ rx) << 3)];
        }
#pragma unroll
        for (int n = 0; n < 4; ++n) {
            int r = wc + n * 16 + fr;
            int rb = r * 64, rx = r & 7;
            bh[n] = *(const short8*)&sB[rb + ((fk3 ^ rx) << 3)];
            bl[n] = *(const short8*)&sB[rb + (((4 | fk3) ^ rx) << 3)];
        }
        __builtin_amdgcn_s_setprio(1);
#pragma unroll
        for (int i = 0; i < 4; ++i)
#pragma unroll
            for (int n = 0; n < 4; ++n) {
                acc[i][n] = MFMA_BF16(ah[i], bh[n], acc[i][n]);
                acc[i][n] = MFMA_BF16(ah[i], bl[n], acc[i][n]);
                acc[i][n] = MFMA_BF16(al[i], bh[n], acc[i][n]);
            }
        __builtin_amdgcn_s_setprio(0);
        // counted wait: next step's 6 loads (oldest) must land; this step's
        // 6 prefetch loads stay in flight across the barrier (never drain to 0)
        if (s < 30) asm volatile("s_waitcnt vmcnt(6)" ::: "memory");
        else        asm volatile("s_waitcnt vmcnt(0)" ::: "memory");
        __builtin_amdgcn_s_barrier();
    }
#undef STAGE

    // ---- epilogue: math in fragment layout, per-wave LDS slab -> coalesced ----
    const float cv = cptr[0];
    const float rcv = sqrtf(cv);
    const float inv_rc = 1.0f / rcv;
    const int fc = l & 15, fq = (l >> 4) * 4;

    float cxr[16];
#pragma unroll
    for (int i = 0; i < 4; ++i)
#pragma unroll
        for (int q = 0; q < 4; ++q)
            cxr[i * 4 + q] = cx2[row0 + wr + i * 16 + fq + q];

    float chf[4], shf[4], wff[4];
#pragma unroll
    for (int n = 0; n < 4; ++n) {
        const int col = col0 + wc + n * 16 + fc;
        float dr = 2.0f * rcv * bias[col];
        chf[n] = coshf(dr) * 2.0f * invn[col];   // folds 2*invn
        shf[n] = sinhf(dr);
        wff[n] = 2.0f * wg[col] * inv_rc;
    }

    // per-wave PRIVATE slab: 16 rows x 64 cols, stride 68 floats, 4.25 KB
    float* slab = (float*)(smem + w * 8192);
    const int rr = l >> 4;          // 0..3 (read-phase row group)
    const int rc16 = l & 15;        // 0..15 (read-phase col group)

#pragma unroll
    for (int i = 0; i < 4; ++i) {
#pragma unroll
        for (int n = 0; n < 4; ++n)
#pragma unroll
            for (int q = 0; q < 4; ++q) {
                float a = acc[i][n][q];
                float mlr = fmaf(a, chf[n], -(1.0f + cxr[i * 4 + q]) * shf[n]);
                float wv = wff[n] * fast_asinh(mlr);
                slab[(fq + q) * 68 + n * 16 + fc] = fast_sinh(rcv * wv) * inv_rc;
            }
        // slab is private to this wave: no cross-wave barrier needed;
        // compiler orders ds_write -> ds_read via may-alias dependence
#pragma unroll
        for (int p = 0; p < 4; ++p) {
            float4 v4 = *(const float4*)&slab[(p * 4 + rr) * 68 + rc16 * 4];
            *(float4*)&Y[(size_t)(row0 + wr + i * 16 + p * 4 + rr) * DIM +
                         col0 + wc + rc16 * 4] = v4;
        }
    }
}

// ---- per-row finalize: denom + relu-in-tangent + logmap0 ----
__global__ void finalize(float* __restrict__ Y, const float* __restrict__ cptr) {
    int row = blockIdx.x;
    float4* rp = (float4*)(Y + (size_t)row * DIM);
    float4 v = rp[threadIdx.x];
    float s1 = v.x * v.x + v.y * v.y + v.z * v.z + v.w * v.w;
    float rx = fmaxf(v.x, 0.f), ryy = fmaxf(v.y, 0.f);
    float rz = fmaxf(v.z, 0.f), rw = fmaxf(v.w, 0.f);
    float s2 = rx * rx + ryy * ryy + rz * rz + rw * rw;
    s1 = waveReduceSum(s1);
    s2 = waveReduceSum(s2);
    __shared__ float red1[4], red2[4];
    int wid = threadIdx.x >> 6, lane = threadIdx.x & 63;
    if (lane == 0) { red1[wid] = s1; red2[wid] = s2; }
    __syncthreads();
    s1 = red1[0] + red1[1] + red1[2] + red1[3];
    s2 = red2[0] + red2[1] + red2[2] + red2[3];

    const float c = cptr[0];
    const float rc = sqrtf(c);
    float g = 1.0f / (1.0f + sqrtf(1.0f + c * s1));     // x = g*y
    float xn = sqrtf(fmaxf(g * g * s1, 1e-15f));
    float arg = fminf(rc * xn, 1.0f - 1e-7f);
    float f1 = atanhf(arg) / (rc * xn);                  // u = f1*x
    float fv = f1 * g;                                   // v = fv*relu(y)
    float vn = sqrtf(fmaxf(fv * fv * s2, 1e-15f));
    float f2 = tanhf(rc * vn) / (rc * vn);               // e = f2*v
    float en = sqrtf(fmaxf(f2 * f2 * fv * fv * s2, 1e-15f));
    float maxnorm = (1.0f - 1e-5f) / rc;
    float pf = (en > maxnorm) ? (maxnorm / en) : 1.0f;   // z = pf*e
    float zn = sqrtf(fmaxf(pf * pf * f2 * f2 * fv * fv * s2, 1e-15f));
    float arg2 = fminf(rc * zn, 1.0f - 1e-7f);
    float f3 = atanhf(arg2) / (rc * zn);                 // out = f3*z
    float F = f3 * pf * f2 * fv;

    rp[threadIdx.x] = make_float4(F * rx, F * ryy, F * rz, F * rw);
}

extern "C" void kernel_launch(void* const* d_in, const int* in_sizes, int n_in,
                              void* d_out, int out_size, void* d_ws, size_t ws_size,
                              hipStream_t stream) {
    const float* inputs   = (const float*)d_in[0];
    const float* weigh_v  = (const float*)d_in[1];
    const float* weight_g = (const float*)d_in[2];
    const float* bias     = (const float*)d_in[3];
    const float* cptr     = (const float*)d_in[4];
    float* Y = (float*)d_out;

    // workspace layout (assumes ws_size >= ~69 MB)
    char* ws = (char*)d_ws;
    short* Aws = (short*)ws;                                      // 64 MB
    short* Bws = (short*)(ws + (size_t)64 * 1024 * 1024);         // 4 MB
    float* invn    = (float*)(ws + (size_t)68 * 1024 * 1024);     // 4 KB
    float* cx2     = (float*)(ws + (size_t)68 * 1024 * 1024 + 65536);   // 64 KB
    float* colpart = (float*)(ws + (size_t)68 * 1024 * 1024 + 131072);  // 32 KB

    colnorm_partial<<<32, 256, 0, stream>>>(weigh_v, colpart);
    colnorm_final<<<4, 256, 0, stream>>>(colpart, invn);
    wsplit<<<256, 256, 0, stream>>>(weigh_v, Bws);
    rowprep_split<<<M_ROWS, 256, 0, stream>>>(inputs, cptr, Aws, cx2);

    gemm_mfma<<<512, 512, 0, stream>>>(Aws, Bws, cx2, invn,
                                       weight_g, bias, cptr, Y);

    finalize<<<M_ROWS, 256, 0, stream>>>(Y, cptr);
}